// Round 1
// baseline (110.903 us; speedup 1.0000x reference)
//
#include <hip/hip_runtime.h>

// Problem constants (fixed by the reference).
#define T_TABLES 26
#define V_VOCAB  1000
#define D_DIM    128
#define B_BATCH  8192
#define L_BAG    8

#define SEG4  (D_DIM / 4)                    // 32 float4 per 128-float segment
#define ROW4  ((T_TABLES + 1) * SEG4)        // 864 float4 per output row

__global__ __launch_bounds__(256)
void EmbCatDense_53309134078326_kernel(
    const int*   __restrict__ indices,   // [T, B, L] int32
    const float* __restrict__ to_cat,    // [B, D]
    const float* __restrict__ tables,    // [T, V, D]
    float*       __restrict__ out)       // [B, (T+1)*D]
{
    __shared__ int idx_lds[T_TABLES * L_BAG];   // 208 ints = 832 B

    const int b   = blockIdx.x;
    const int tid = threadIdx.x;

    // Stage this row's 26*8 bag indices into LDS once.
    if (tid < T_TABLES * L_BAG) {
        const int t = tid >> 3;      // table
        const int l = tid & 7;       // position in bag
        idx_lds[tid] = indices[((size_t)t * B_BATCH + b) * L_BAG + l];
    }
    __syncthreads();

    const float4* tab4 = reinterpret_cast<const float4*>(tables);
    const float4* cat4 = reinterpret_cast<const float4*>(to_cat);
    float4*       out4 = reinterpret_cast<float4*>(out);

    // 864 float4 per row, 256 threads -> 3-4 iterations each, coalesced.
    for (int col4 = tid; col4 < ROW4; col4 += 256) {
        const int seg    = col4 >> 5;   // 0 = dense, 1..26 = tables
        const int within = col4 & 31;   // float4 index inside the 128-float segment
        float4 v;
        if (seg == 0) {
            v = cat4[(size_t)b * SEG4 + within];
        } else {
            const int t = seg - 1;
            const float4* base = tab4 + (size_t)t * V_VOCAB * SEG4 + within;
            float4 acc = make_float4(0.f, 0.f, 0.f, 0.f);
            #pragma unroll
            for (int l = 0; l < L_BAG; ++l) {
                const int r = idx_lds[t * L_BAG + l];   // broadcast across 32 lanes
                const float4 e = base[(size_t)r * SEG4];
                acc.x += e.x; acc.y += e.y; acc.z += e.z; acc.w += e.w;
            }
            v = acc;
        }
        out4[(size_t)b * ROW4 + col4] = v;
    }
}

extern "C" void kernel_launch(void* const* d_in, const int* in_sizes, int n_in,
                              void* d_out, int out_size, void* d_ws, size_t ws_size,
                              hipStream_t stream) {
    const int*   indices = (const int*)  d_in[0];
    // d_in[1] = offsets [T, B] — encodes fixed bag length L, unused.
    const float* to_cat  = (const float*)d_in[2];
    const float* tables  = (const float*)d_in[3];
    float*       out     = (float*)      d_out;

    EmbCatDense_53309134078326_kernel<<<B_BATCH, 256, 0, stream>>>(
        indices, to_cat, tables, out);
}

// Round 2
// 47.238 us; speedup vs baseline: 2.3478x; 2.3478x over previous
//
#include <hip/hip_runtime.h>

// Problem constants (fixed by the reference).
#define T_TABLES 26
#define V_VOCAB  1000
#define D_DIM    128
#define B_BATCH  8192
#define L_BAG    8

#define SEG4   (D_DIM / 4)                 // 32 float4 per 128-float segment
#define ROW4   ((T_TABLES + 1) * SEG4)     // 864 float4 per output row
#define NXCD   8
#define CHUNK  256                         // batch rows per block
#define NCH    (B_BATCH / CHUNK)           // 32 chunks
#define SLOTS  128                         // max tables-per-xcd (4) * NCH

// One block = one (table, batch-chunk) pair, placed so that all blocks of a
// given table land on the same XCD (blockIdx % 8 round-robin): per-XCD live
// table footprint is 3-4 tables * 512 KB = 1.5-2 MB < 4 MiB L2.
__global__ __launch_bounds__(256)
void EmbCatDense_53309134078326_kernel(
    const int*   __restrict__ indices,   // [T, B, L] int32
    const float* __restrict__ to_cat,    // [B, D]
    const float* __restrict__ tables,    // [T, V, D]
    float*       __restrict__ out)       // [B, (T+1)*D]
{
    __shared__ int idx_lds[CHUNK * L_BAG];   // 8 KB

    const int bid  = blockIdx.x;
    const int xcd  = bid & (NXCD - 1);
    const int slot = bid >> 3;
    const int tid  = threadIdx.x;

    const int ntab = (xcd < 2) ? 4 : 3;      // #tables t with t%8==xcd, t<26
    const int lane = tid & 31;               // float4 column within segment
    const int grp  = tid >> 5;               // 0..7: row group

    if (slot < ntab * NCH) {
        // ---- embedding-bag work: table t, batch rows [b0, b0+CHUNK) ----
        const int t  = xcd + NXCD * (slot >> 5);
        const int c  = slot & (NCH - 1);
        const int b0 = c * CHUNK;

        // Stage this chunk's 256*8 indices (8 KB, contiguous) into LDS.
        const int4* ip = reinterpret_cast<const int4*>(
            indices + ((size_t)t * B_BATCH + b0) * L_BAG);
        int4* lp = reinterpret_cast<int4*>(idx_lds);
        lp[tid]       = ip[tid];
        lp[tid + 256] = ip[tid + 256];
        __syncthreads();

        const float4* tb = reinterpret_cast<const float4*>(tables)
                         + (size_t)t * (V_VOCAB * SEG4) + lane;
        float4* o4 = reinterpret_cast<float4*>(out)
                   + (size_t)(t + 1) * SEG4 + lane;

        for (int i = 0; i < CHUNK / 8; ++i) {
            const int j = i * 8 + grp;                 // row within chunk
            float4 acc = make_float4(0.f, 0.f, 0.f, 0.f);
            #pragma unroll
            for (int l = 0; l < L_BAG; ++l) {
                const int r = idx_lds[j * L_BAG + l];  // broadcast in 32-group
                const float4 e = tb[(size_t)r * SEG4]; // 512 B coalesced, L2-hot
                acc.x += e.x; acc.y += e.y; acc.z += e.z; acc.w += e.w;
            }
            o4[(size_t)(b0 + j) * ROW4] = acc;         // full-line write
        }
    } else if (xcd >= 2) {
        // ---- dense to_cat copy: spare slots on xcd 2..7 ----
        const int spare = slot - ntab * NCH;           // 0..31
        if (spare < 6) {
            const int cc = (xcd - 2) * 6 + spare;      // dense chunk id
            if (cc < NCH) {
                const int b0 = cc * CHUNK;
                const float4* c4 = reinterpret_cast<const float4*>(to_cat) + lane;
                float4* o4 = reinterpret_cast<float4*>(out) + lane;
                for (int i = 0; i < CHUNK / 8; ++i) {
                    const size_t j = (size_t)(b0 + i * 8 + grp);
                    o4[j * ROW4] = c4[j * SEG4];
                }
            }
        }
    }
}

extern "C" void kernel_launch(void* const* d_in, const int* in_sizes, int n_in,
                              void* d_out, int out_size, void* d_ws, size_t ws_size,
                              hipStream_t stream) {
    const int*   indices = (const int*)  d_in[0];
    // d_in[1] = offsets [T, B] — encodes fixed bag length L, unused.
    const float* to_cat  = (const float*)d_in[2];
    const float* tables  = (const float*)d_in[3];
    float*       out     = (float*)      d_out;

    EmbCatDense_53309134078326_kernel<<<NXCD * SLOTS, 256, 0, stream>>>(
        indices, to_cat, tables, out);
}